// Round 8
// baseline (82.563 us; speedup 1.0000x reference)
//
#include <hip/hip_runtime.h>
#include <hip/hip_fp16.h>

typedef __attribute__((ext_vector_type(8))) _Float16 half8;
typedef __attribute__((ext_vector_type(4))) float f32x4;

union U2H2 { unsigned int u; __half2 h; };

static __device__ __forceinline__ unsigned int pack2h(float a, float b) {
    U2H2 c; c.h = __floats2half2_rn(a, b); return c.u;
}
static __device__ __forceinline__ __half2 u_as_h2(unsigned int u) {
    U2H2 c; c.u = u; return c.h;
}
static __device__ __forceinline__ __half2 hi16(unsigned int u) {
    return u_as_h2(__builtin_amdgcn_perm(u, u, 0x03020302u));
}

// Fused prep: blocks [0,nT) transpose x -> xth [N][2][32] fp16;
// blocks [nT,nT+25) repack W -> fragment-ordered Wrh[k][ot][l][8] fp16,
//   o = ot*16 + (l&15), c = (l>>4)*8 + e.
__global__ __launch_bounds__(256) void prep_all(const float* __restrict__ x,
                                                const float* __restrict__ W,
                                                unsigned short* __restrict__ xth,
                                                unsigned short* __restrict__ Wrh,
                                                int N, int nT) {
    int bid = blockIdx.x, tid = threadIdx.x;
    if (bid >= nT) {
        int k = bid - nT;  // 0..24
#pragma unroll
        for (int it = 0; it < 8; ++it) {
            int r = tid + 256 * it;          // 0..2047
            int ot = r >> 9, lx = (r >> 3) & 63, e = r & 7;
            int o = ot * 16 + (lx & 15);
            int c = (lx >> 4) * 8 + e;
            __half h = __float2half(W[o * 800 + c * 25 + k]);
            Wrh[k * 2048 + r] = *reinterpret_cast<unsigned short*>(&h);
        }
        return;
    }
    __shared__ float t[2][32][65];
    int n0 = bid * 64;
#pragma unroll
    for (int i = 0; i < 16; ++i) {
        int e = tid + 256 * i;               // [2][32][64]
        int b = e >> 11, c = (e >> 6) & 31, nl = e & 63;
        int n = n0 + nl;
        t[b][c][nl] = (n < N) ? x[(size_t)(b * 32 + c) * N + n] : 0.f;
    }
    __syncthreads();
    int nl = tid >> 2, q = tid & 3, n = n0 + nl;
    if (n < N) {
#pragma unroll
        for (int b = 0; b < 2; ++b) {
            uint4 p;
            p.x = pack2h(t[b][q * 8 + 0][nl], t[b][q * 8 + 1][nl]);
            p.y = pack2h(t[b][q * 8 + 2][nl], t[b][q * 8 + 3][nl]);
            p.z = pack2h(t[b][q * 8 + 4][nl], t[b][q * 8 + 5][nl]);
            p.w = pack2h(t[b][q * 8 + 6][nl], t[b][q * 8 + 7][nl]);
            *reinterpret_cast<uint4*>(xth + ((size_t)n * 64 + b * 32 + q * 8)) = p;
        }
    }
}

// Persistent fused kernel: W resident in LDS (100 KB), 8 independent waves,
// wave-local A staging (no s_barrier in the k-loop). Each block loops tiles.
__global__ __launch_bounds__(512, 1) void fused_main(
    const unsigned short* __restrict__ xth,  // [N][2][32] fp16
    const unsigned short* __restrict__ Wrh,  // [25][4][64][8] fp16 (fragment order)
    const float* __restrict__ bias,          // [64]
    const int* __restrict__ nidx,            // [N][25][3]
    const float* __restrict__ nw,            // [N][25][3]
    float* __restrict__ out,                 // [2][64][N] fp32
    int N, int ntiles)
{
    __shared__ __align__(16) unsigned short wlds[25 * 2048];  // 102400 B, whole W
    __shared__ __align__(16) unsigned int   idxw[64 * 100];   // 25600 B, [nl][25][4]
    __shared__ __align__(16) unsigned char  sA[8 * 1280];     // 10240 B, wave-private

    const int tid = threadIdx.x;

    // ---- load all of W into LDS once (visible after the first tile barrier) ----
    {
        const uint4* src = reinterpret_cast<const uint4*>(Wrh);
        uint4* dst = reinterpret_cast<uint4*>(wlds);
        for (int i = tid; i < 6400; i += 512) dst[i] = src[i];
    }

    const int wv = tid >> 6, l = tid & 63;
    const int b0  = wv >> 2;            // wave-uniform batch half
    const int nlb = (wv & 3) * 16;      // wave's nl base within the 64-n tile
    const int r16 = l >> 2, q = l & 3;  // gather row / 16B quad slice
    const int nl0 = nlb + r16;
    const int c16 = l & 15, g = l >> 4;

    unsigned char* sAw = sA + wv * 1280;            // wave-private region
    const int aw_off = r16 * 80 + q * 16;           // staging write (row stride 80)
    const int ar_off = c16 * 80 + g * 16;           // fragment read

    const unsigned short* xb = xth + b0 * 32 + q * 8;  // + j*64 per gather
    const unsigned int* iqp0 = &idxw[nl0 * 100];

    float bv[4];
#pragma unroll
    for (int ot = 0; ot < 4; ++ot) bv[ot] = bias[ot * 16 + c16];

    for (int tile = blockIdx.x; tile < ntiles; tile += gridDim.x) {
        const int n0 = tile * 64;

        __syncthreads();  // protect idxw from previous tile's readers
        // ---- stage packed (idx, half(w)) as [nl][25][4] words ----
        for (int it = 0; it < 13; ++it) {
            int e = tid + 512 * it;
            if (e < 6400) {
                int nl = e / 100, r = e - nl * 100;
                int kk = r >> 2, t = r & 3;
                int n = n0 + nl;
                unsigned int u = 0;
                if (t < 3 && n < N) {
                    size_t s = (size_t)n * 75 + kk * 3 + t;
                    int j = nidx[s];
                    __half hw = __float2half(nw[s]);
                    u = (unsigned int)j |
                        ((unsigned int)*reinterpret_cast<unsigned short*>(&hw) << 16);
                }
                idxw[e] = u;
            }
        }
        __syncthreads();  // idxw ready (and W ready on first tile)

        f32x4 acc[4];
#pragma unroll
        for (int ot = 0; ot < 4; ++ot) acc[ot] = (f32x4){0.f, 0.f, 0.f, 0.f};

        uint4 riq[3], rg[3][3];

        // ---- prologue: iq + gathers for slices 0..2 ----
#pragma unroll
        for (int kk = 0; kk < 3; ++kk)
            riq[kk] = *reinterpret_cast<const uint4*>(iqp0 + kk * 4);
        asm volatile("s_waitcnt lgkmcnt(0)" ::: "memory");
        __builtin_amdgcn_sched_barrier(0);
#pragma unroll
        for (int kk = 0; kk < 3; ++kk) {
            rg[kk][0] = *reinterpret_cast<const uint4*>(xb + (riq[kk].x & 0xffffu) * 64);
            rg[kk][1] = *reinterpret_cast<const uint4*>(xb + (riq[kk].y & 0xffffu) * 64);
            rg[kk][2] = *reinterpret_cast<const uint4*>(xb + (riq[kk].z & 0xffffu) * 64);
        }

#pragma unroll
        for (int k = 0; k < 25; ++k) {
            const int gb = k % 3;

            // weighted fp16 sum -> A slice (this wave's 16 rows x 32 c)
            __half2 w0 = hi16(riq[gb].x), w1 = hi16(riq[gb].y), w2 = hi16(riq[gb].z);
            uint4 v0 = rg[gb][0], v1 = rg[gb][1], v2 = rg[gb][2];
            uint4 p; U2H2 c;
            c.h = __hfma2(u_as_h2(v0.x), w0, __hfma2(u_as_h2(v1.x), w1, __hmul2(u_as_h2(v2.x), w2)));
            p.x = c.u;
            c.h = __hfma2(u_as_h2(v0.y), w0, __hfma2(u_as_h2(v1.y), w1, __hmul2(u_as_h2(v2.y), w2)));
            p.y = c.u;
            c.h = __hfma2(u_as_h2(v0.z), w0, __hfma2(u_as_h2(v1.z), w1, __hmul2(u_as_h2(v2.z), w2)));
            p.z = c.u;
            c.h = __hfma2(u_as_h2(v0.w), w0, __hfma2(u_as_h2(v1.w), w1, __hmul2(u_as_h2(v2.w), w2)));
            p.w = c.u;
            *reinterpret_cast<uint4*>(sAw + aw_off) = p;

            // refill iq for slice k+3
            if (k + 3 < 25)
                riq[gb] = *reinterpret_cast<const uint4*>(iqp0 + (k + 3) * 4);

            // wave-local fence: A-write + iq-read complete; no s_barrier
            asm volatile("s_waitcnt lgkmcnt(0)" ::: "memory");
            __builtin_amdgcn_sched_barrier(0);

            // refill gathers for slice k+3 (stay in flight across MFMA)
            if (k + 3 < 25) {
                rg[gb][0] = *reinterpret_cast<const uint4*>(xb + (riq[gb].x & 0xffffu) * 64);
                rg[gb][1] = *reinterpret_cast<const uint4*>(xb + (riq[gb].y & 0xffffu) * 64);
                rg[gb][2] = *reinterpret_cast<const uint4*>(xb + (riq[gb].z & 0xffffu) * 64);
            }

            // MFMA: A from wave-private LDS, B from resident W-LDS
            half8 af = *reinterpret_cast<const half8*>(sAw + ar_off);
            __builtin_amdgcn_s_setprio(1);
#pragma unroll
            for (int ot = 0; ot < 4; ++ot) {
                half8 bf = *reinterpret_cast<const half8*>(wlds + k * 2048 + ot * 512 + l * 8);
                acc[ot] = __builtin_amdgcn_mfma_f32_16x16x32_f16(af, bf, acc[ot], 0, 0, 0);
            }
            __builtin_amdgcn_s_setprio(0);
        }

        // ---- epilogue: bias + store (D: o = ot*16+c16, row = 16wv + 4g + i) ----
#pragma unroll
        for (int ot = 0; ot < 4; ++ot) {
            int o = ot * 16 + c16;
#pragma unroll
            for (int i = 0; i < 4; ++i) {
                int grow = 16 * wv + 4 * g + i;
                int b = grow >> 6, nl = grow & 63;
                int n = n0 + nl;
                if (n < N) out[(size_t)(b * 64 + o) * N + n] = acc[ot][i] + bv[ot];
            }
        }
    }
}

extern "C" void kernel_launch(void* const* d_in, const int* in_sizes, int n_in,
                              void* d_out, int out_size, void* d_ws, size_t ws_size,
                              hipStream_t stream) {
    const float* x    = (const float*)d_in[0];   // (2,32,N)
    const float* nw   = (const float*)d_in[1];   // (N,25,3)
    const float* W    = (const float*)d_in[2];   // (64,800)
    const float* bias = (const float*)d_in[3];   // (64,)
    const int*   nidx = (const int*)d_in[4];     // (N,25,3)
    float* out = (float*)d_out;

    int N = in_sizes[0] / 64;  // B*C = 64

    unsigned short* xth = (unsigned short*)d_ws;      // [N][2][32] fp16
    unsigned short* Wrh = xth + (size_t)N * 64;       // [25][4][64][8] fp16

    int nT = (N + 63) / 64;
    prep_all<<<nT + 25, 256, 0, stream>>>(x, W, xth, Wrh, N, nT);

    int ntiles = (N + 63) / 64;
    int grid = ntiles < 256 ? ntiles : 256;
    fused_main<<<grid, 512, 0, stream>>>(xth, Wrh, bias, nidx, nw, out, N, ntiles);
}

// Round 9
// 64.865 us; speedup vs baseline: 1.2729x; 1.2729x over previous
//
#include <hip/hip_runtime.h>
#include <hip/hip_fp16.h>

typedef __attribute__((ext_vector_type(8))) _Float16 half8;
typedef __attribute__((ext_vector_type(4))) float f32x4;

union U2H2 { unsigned int u; __half2 h; };

static __device__ __forceinline__ unsigned int pack2h(float a, float b) {
    U2H2 c; c.h = __floats2half2_rn(a, b); return c.u;
}
static __device__ __forceinline__ __half2 u_as_h2(unsigned int u) {
    U2H2 c; c.u = u; return c.h;
}
static __device__ __forceinline__ __half2 hi16(unsigned int u) {
    return u_as_h2(__builtin_amdgcn_perm(u, u, 0x03020302u));
}

// swizzle: slot' = slot ^ s(row), s(row)=(row&3)^((row>>2)&3) (conflict-free for
// the 4-lane-per-row write and the 16-row stride-64B fragment read)
#define SWZ(row, slot) ((slot) ^ ((row) & 3) ^ (((row) >> 2) & 3))

// fence LDS + barrier WITHOUT draining vmcnt (prefetched gathers stay in flight)
#define LDS_BARRIER()                                                \
    do {                                                             \
        asm volatile("s_waitcnt lgkmcnt(0)" ::: "memory");           \
        __builtin_amdgcn_s_barrier();                                \
        __builtin_amdgcn_sched_barrier(0);                           \
    } while (0)

// Fused prep: blocks [0,nT): transpose x -> xth [B][N][32] fp16 (per-b planes);
// blocks [nT,nT+25): repack W -> Wrh[k][o][c] fp16.
__global__ __launch_bounds__(256) void prep_all(const float* __restrict__ x,
                                                const float* __restrict__ W,
                                                unsigned short* __restrict__ xth,
                                                unsigned short* __restrict__ Wrh,
                                                int N, int nT) {
    int bid = blockIdx.x, tid = threadIdx.x;
    if (bid >= nT) {
        int k = bid - nT;  // 0..24
#pragma unroll
        for (int it = 0; it < 8; ++it) {
            int r = tid + 256 * it;          // 0..2047 = o*32+c
            int o = r >> 5, c = r & 31;
            __half h = __float2half(W[o * 800 + c * 25 + k]);
            Wrh[k * 2048 + r] = *reinterpret_cast<unsigned short*>(&h);
        }
        return;
    }
    __shared__ float t[2][32][65];
    int n0 = bid * 64;
#pragma unroll
    for (int i = 0; i < 16; ++i) {
        int e = tid + 256 * i;               // [2][32][64]
        int b = e >> 11, c = (e >> 6) & 31, nl = e & 63;
        int n = n0 + nl;
        t[b][c][nl] = (n < N) ? x[(size_t)(b * 32 + c) * N + n] : 0.f;
    }
    __syncthreads();
    int nl = tid >> 2, q = tid & 3, n = n0 + nl;
    if (n < N) {
#pragma unroll
        for (int b = 0; b < 2; ++b) {
            uint4 p;
            p.x = pack2h(t[b][q * 8 + 0][nl], t[b][q * 8 + 1][nl]);
            p.y = pack2h(t[b][q * 8 + 2][nl], t[b][q * 8 + 3][nl]);
            p.z = pack2h(t[b][q * 8 + 4][nl], t[b][q * 8 + 5][nl]);
            p.w = pack2h(t[b][q * 8 + 6][nl], t[b][q * 8 + 7][nl]);
            *reinterpret_cast<uint4*>(xth + (((size_t)b * N + n) * 32 + q * 8)) = p;
        }
    }
}

// Fused gather + einsum + MFMA + bias. One batch-half per block, partitioned
// across XCDs so each XCD's gathers touch only a 2.6 MB (L2-resident) plane.
__global__ __launch_bounds__(256) void fused_main(
    const unsigned short* __restrict__ xth,  // [2][N][32] fp16
    const unsigned short* __restrict__ Wrh,  // [25][64][32] fp16
    const float* __restrict__ bias,          // [64]
    const int* __restrict__ nidx,            // [N][25][3]
    const float* __restrict__ nw,            // [N][25][3]
    float* __restrict__ out,                 // [2][64][N] fp32
    int N, int nt)
{
    __shared__ unsigned int idxw[64 * 75];                  // [nl][75]: j | half(w)<<16
    __shared__ __align__(16) unsigned char sA[2][4096];     // dbuf A slice (64n x 32c)
    __shared__ __align__(16) unsigned char sB[2][4096];     // dbuf B slice (64o x 32c)

    const int bid = blockIdx.x;
    const int b0 = (bid & 7) >> 2;                  // XCDs 0-3 -> b=0, 4-7 -> b=1
    const int tile = (bid >> 3) * 4 + (bid & 3);
    if (tile >= nt) return;
    const int n0 = tile * 64;
    const int tid = threadIdx.x;

    // ---- stage packed (idx, half(w)): 64 n x 75 words ----
#pragma unroll
    for (int it = 0; it < 19; ++it) {
        int e = tid + 256 * it;
        if (e < 4800) {
            int n = n0 + e / 75;
            unsigned int u = 0;
            if (n < N) {
                size_t s = (size_t)n0 * 75 + e;
                int j = nidx[s];
                __half hw = __float2half(nw[s]);
                u = (unsigned int)j |
                    ((unsigned int)*reinterpret_cast<unsigned short*>(&hw) << 16);
            }
            idxw[e] = u;
        }
    }
    __syncthreads();

    const int row = tid >> 2;          // n-row 0..63 this thread gathers
    const int q   = tid & 3;           // 16B quad-slice of the 64B row
    const int wr_off = row * 64 + (SWZ(row, q) << 4);   // sA/sB write offset

    const int l = tid & 63, wv = tid >> 6, c16 = l & 15, g = l >> 4;
    const int arow = 16 * wv + c16;                     // wave-local A rows
    const int rd_a = arow * 64 + (SWZ(arow, g) << 4);

    const unsigned short* xb = xth + (size_t)b0 * N * 32 + q * 8;  // + j*32
    const unsigned int* iprow = &idxw[row * 75];

    unsigned int ru[3][3];
    uint4 rg[3][3];
    uint4 rB;

    f32x4 acc[4];
#pragma unroll
    for (int ot = 0; ot < 4; ++ot) acc[ot] = (f32x4){0.f, 0.f, 0.f, 0.f};

    // ---- prologue: B(0); idx+gathers for slices 0..2 ----
    rB = *reinterpret_cast<const uint4*>(Wrh + tid * 8);
#pragma unroll
    for (int kk = 0; kk < 3; ++kk)
#pragma unroll
        for (int t = 0; t < 3; ++t) ru[kk][t] = iprow[kk * 3 + t];
#pragma unroll
    for (int kk = 0; kk < 3; ++kk)
#pragma unroll
        for (int t = 0; t < 3; ++t)
            rg[kk][t] = *reinterpret_cast<const uint4*>(xb + (ru[kk][t] & 0xffffu) * 32);

#pragma unroll
    for (int k = 0; k < 25; ++k) {
        const int gb = k % 3, buf = k & 1;

        // consume rB -> sB[buf]; refill B(k+1)
        *reinterpret_cast<uint4*>(&sB[buf][wr_off]) = rB;
        if (k + 1 < 25)
            rB = *reinterpret_cast<const uint4*>(Wrh + (k + 1) * 2048 + tid * 8);

        // weighted fp16 sum of the 3 gathered slices -> sA[buf]
        {
            __half2 w0 = hi16(ru[gb][0]), w1 = hi16(ru[gb][1]), w2 = hi16(ru[gb][2]);
            uint4 v0 = rg[gb][0], v1 = rg[gb][1], v2 = rg[gb][2];
            uint4 p; U2H2 c;
            c.h = __hfma2(u_as_h2(v0.x), w0, __hfma2(u_as_h2(v1.x), w1, __hmul2(u_as_h2(v2.x), w2)));
            p.x = c.u;
            c.h = __hfma2(u_as_h2(v0.y), w0, __hfma2(u_as_h2(v1.y), w1, __hmul2(u_as_h2(v2.y), w2)));
            p.y = c.u;
            c.h = __hfma2(u_as_h2(v0.z), w0, __hfma2(u_as_h2(v1.z), w1, __hmul2(u_as_h2(v2.z), w2)));
            p.z = c.u;
            c.h = __hfma2(u_as_h2(v0.w), w0, __hfma2(u_as_h2(v1.w), w1, __hmul2(u_as_h2(v2.w), w2)));
            p.w = c.u;
            *reinterpret_cast<uint4*>(&sA[buf][wr_off]) = p;
        }

        // idx words for slice k+3 (LDS read completes at the barrier fence)
        if (k + 3 < 25) {
#pragma unroll
            for (int t = 0; t < 3; ++t) ru[gb][t] = iprow[(k + 3) * 3 + t];
        }

        // one barrier: sA/sB visible + idx ready; vmem prefetch stays in flight
        LDS_BARRIER();

        // issue gathers for slice k+3 immediately (no wait: lgkm already drained)
        if (k + 3 < 25) {
#pragma unroll
            for (int t = 0; t < 3; ++t)
                rg[gb][t] = *reinterpret_cast<const uint4*>(xb + (ru[gb][t] & 0xffffu) * 32);
        }

        // MFMA: A wave-local rows, B shared slice
        {
            half8 af = *reinterpret_cast<const half8*>(&sA[buf][rd_a]);
            __builtin_amdgcn_s_setprio(1);
#pragma unroll
            for (int ot = 0; ot < 4; ++ot) {
                int orow = ot * 16 + c16;
                half8 bf = *reinterpret_cast<const half8*>(
                    &sB[buf][orow * 64 + (SWZ(orow, g) << 4)]);
                acc[ot] = __builtin_amdgcn_mfma_f32_16x16x32_f16(af, bf, acc[ot], 0, 0, 0);
            }
            __builtin_amdgcn_s_setprio(0);
        }
    }

    // ---- epilogue: bias + store (D: o = ot*16+c16, n-row = 16wv+4g+i) ----
#pragma unroll
    for (int ot = 0; ot < 4; ++ot) {
        int o = ot * 16 + c16;
        float bv = bias[o];
#pragma unroll
        for (int i = 0; i < 4; ++i) {
            int n = n0 + 16 * wv + 4 * g + i;
            if (n < N) out[((size_t)b0 * 64 + o) * N + n] = acc[ot][i] + bv;
        }
    }
}

extern "C" void kernel_launch(void* const* d_in, const int* in_sizes, int n_in,
                              void* d_out, int out_size, void* d_ws, size_t ws_size,
                              hipStream_t stream) {
    const float* x    = (const float*)d_in[0];   // (2,32,N)
    const float* nw   = (const float*)d_in[1];   // (N,25,3)
    const float* W    = (const float*)d_in[2];   // (64,800)
    const float* bias = (const float*)d_in[3];   // (64,)
    const int*   nidx = (const int*)d_in[4];     // (N,25,3)
    float* out = (float*)d_out;

    int N = in_sizes[0] / 64;  // B*C = 64

    unsigned short* xth = (unsigned short*)d_ws;      // [2][N][32] fp16
    unsigned short* Wrh = xth + (size_t)2 * N * 32;   // [25][64][32] fp16

    int nT = (N + 63) / 64;
    prep_all<<<nT + 25, 256, 0, stream>>>(x, W, xth, Wrh, N, nT);

    int nt = (N + 63) / 64;                 // tiles per batch half
    int grid = ((nt + 3) / 4) * 8;          // 8-block groups: 4 tiles x 2 halves
    fused_main<<<grid, 256, 0, stream>>>(xth, Wrh, bias, nidx, nw, out, N, nt);
}